// Round 1
// baseline (2995.633 us; speedup 1.0000x reference)
//
#include <hip/hip_runtime.h>
#include <cmath>

#define S_LEN 2048
#define E_DIM 512
#define B_SZ 4
#define CIN_D 64
#define COUT_D 64
#define L_NUM 4
#define CHK 256
#define NCHK 8
#define ROWS (B_SZ * S_LEN)  // 8192

// ---------------- activation helpers ----------------
// ACT: 0 = none, 1 = phi (elu+1), 2 = gelu (exact, erf-based)
template <int ACT>
__device__ __forceinline__ float act_f(float x) {
  if (ACT == 1) return x > 0.f ? x + 1.f : __expf(x);
  if (ACT == 2) return 0.5f * x * (1.f + erff(x * 0.70710678118654752f));
  return x;
}

#define TSTORE(SM, vv, r, c0) \
  SM[(c0) + 0][r] = vv.x;     \
  SM[(c0) + 1][r] = vv.y;     \
  SM[(c0) + 2][r] = vv.z;     \
  SM[(c0) + 3][r] = vv.w;

// ---------------- generic tiled GEMM: C[m,n] (op)= act(sum_k A[m+off,k]*W[n,k] + bias[n])
// MODE: 0 store, 1 add.  SHIFT: treat rows with (m mod S)+off < 0 as zero (causal conv taps).
template <int MODE, int ACT, bool SHIFT>
__global__ __launch_bounds__(256) void gemm_nt(const float* __restrict__ A,
                                               const float* __restrict__ W,
                                               const float* __restrict__ bias,
                                               float* __restrict__ C, int M, int N,
                                               int K, int row_off) {
  __shared__ float As[16][64];
  __shared__ float Ws[16][64];
  const int tid = threadIdx.x;
  const int tm = tid >> 4, tn = tid & 15;
  const int lr = tid >> 2, lc = (tid & 3) << 2;
  const int bm = blockIdx.x << 6, bn = blockIdx.y << 6;
  float acc[4][4] = {{0.f}};
  for (int k0 = 0; k0 < K; k0 += 16) {
    float4 av;
    const int ar = bm + lr;
    bool ok = true;
    if (SHIFT) {
      int s = ar & (S_LEN - 1);
      ok = (s + row_off) >= 0;
    }
    if (ok)
      av = *(const float4*)(A + (size_t)(ar + row_off) * K + k0 + lc);
    else
      av = make_float4(0.f, 0.f, 0.f, 0.f);
    TSTORE(As, av, lr, lc);
    const float4 wv = *(const float4*)(W + (size_t)(bn + lr) * K + k0 + lc);
    TSTORE(Ws, wv, lr, lc);
    __syncthreads();
#pragma unroll
    for (int kk = 0; kk < 16; ++kk) {
      const float4 a4 = *(const float4*)&As[kk][tm << 2];
      const float4 b4 = *(const float4*)&Ws[kk][tn << 2];
      const float aa[4] = {a4.x, a4.y, a4.z, a4.w};
      const float bb[4] = {b4.x, b4.y, b4.z, b4.w};
#pragma unroll
      for (int i = 0; i < 4; ++i)
#pragma unroll
        for (int j = 0; j < 4; ++j) acc[i][j] += aa[i] * bb[j];
    }
    __syncthreads();
  }
#pragma unroll
  for (int i = 0; i < 4; ++i) {
    const int row = bm + (tm << 2) + i;
    float* crow = C + (size_t)row * N + bn + (tn << 2);
#pragma unroll
    for (int j = 0; j < 4; ++j) {
      float vsum = acc[i][j];
      if (bias) vsum += bias[bn + (tn << 2) + j];
      vsum = act_f<ACT>(vsum);
      if (MODE == 0)
        crow[j] = vsum;
      else
        crow[j] += vsum;
    }
  }
}

// ---------------- x[B,CIN,S] -> xT[B,S,CIN] ----------------
__global__ __launch_bounds__(256) void transpose_x(const float* __restrict__ x,
                                                   float* __restrict__ xT) {
  __shared__ float t[64][65];
  const int b = blockIdx.z, s0 = blockIdx.x << 6, tid = threadIdx.x;
#pragma unroll
  for (int i = 0; i < 16; ++i) {
    int idx = tid + (i << 8);
    int c = idx >> 6, s = idx & 63;
    t[c][s] = x[(((size_t)(b * CIN_D + c)) << 11) + s0 + s];
  }
  __syncthreads();
#pragma unroll
  for (int i = 0; i < 16; ++i) {
    int idx = tid + (i << 8);
    int s = idx >> 6, c = idx & 63;
    xT[(((size_t)(b * S_LEN + s0 + s)) << 6) + c] = t[c][s];
  }
}

// ---------------- repack cc_W[E,E,3] -> w0,w1,w2 each [E,E] ----------------
__global__ void repack_ccw(const float* __restrict__ cw, float* __restrict__ w0,
                           float* __restrict__ w1, float* __restrict__ w2) {
  const int idx = blockIdx.x * 256 + threadIdx.x;  // < E*E
  w0[idx] = cw[3 * idx + 0];
  w1[idx] = cw[3 * idx + 1];
  w2[idx] = cw[3 * idx + 2];
}

// ---------------- layernorm over last dim (512), one block per row ----------------
__global__ __launch_bounds__(256) void layernorm_k(const float* __restrict__ x,
                                                   const float* __restrict__ g,
                                                   const float* __restrict__ bb,
                                                   float* __restrict__ y) {
  const int row = blockIdx.x, tid = threadIdx.x;
  const float2 v = *(const float2*)(x + (((size_t)row) << 9) + (tid << 1));
  float s = v.x + v.y, q = v.x * v.x + v.y * v.y;
#pragma unroll
  for (int off = 32; off; off >>= 1) {
    s += __shfl_down(s, off);
    q += __shfl_down(q, off);
  }
  __shared__ float rs[4], rq[4], mv[2];
  const int wid = tid >> 6, lane = tid & 63;
  if (lane == 0) {
    rs[wid] = s;
    rq[wid] = q;
  }
  __syncthreads();
  if (tid == 0) {
    float S_ = rs[0] + rs[1] + rs[2] + rs[3];
    float Q_ = rq[0] + rq[1] + rq[2] + rq[3];
    float m = S_ * (1.f / 512.f);
    float var = Q_ * (1.f / 512.f) - m * m;
    mv[0] = m;
    mv[1] = rsqrtf(var + 1e-5f);
  }
  __syncthreads();
  const float m = mv[0], r = mv[1];
  const int c = tid << 1;
  float2 o;
  o.x = (v.x - m) * r * g[c] + bb[c];
  o.y = (v.y - m) * r * g[c + 1] + bb[c + 1];
  *(float2*)(y + (((size_t)row) << 9) + c) = o;
}

// ---------------- pass A: per-chunk KV_j[e,e'] = sum_t k[t,e] v[t,e'] ----------------
__global__ __launch_bounds__(256) void chunk_kv(const float* __restrict__ k,
                                                const float* __restrict__ v,
                                                float* __restrict__ P) {
  const int bj = blockIdx.z;
  const int b = bj >> 3, j = bj & 7;
  const int be = blockIdx.x << 6, bep = blockIdx.y << 6;
  const int tid = threadIdx.x, tm = tid >> 4, tn = tid & 15;
  const int lr = tid >> 4, lc = (tid & 15) << 2;
  __shared__ float Ks[16][64], Vs[16][64];
  float acc[4][4] = {{0.f}};
  const size_t base = ((size_t)(b * S_LEN + j * CHK)) << 9;
  for (int t0 = 0; t0 < CHK; t0 += 16) {
    *(float4*)&Ks[lr][lc] =
        *(const float4*)(k + base + (((size_t)(t0 + lr)) << 9) + be + lc);
    *(float4*)&Vs[lr][lc] =
        *(const float4*)(v + base + (((size_t)(t0 + lr)) << 9) + bep + lc);
    __syncthreads();
#pragma unroll
    for (int tt = 0; tt < 16; ++tt) {
      const float4 a4 = *(const float4*)&Ks[tt][tm << 2];
      const float4 b4 = *(const float4*)&Vs[tt][tn << 2];
      const float aa[4] = {a4.x, a4.y, a4.z, a4.w};
      const float bb[4] = {b4.x, b4.y, b4.z, b4.w};
#pragma unroll
      for (int i = 0; i < 4; ++i)
#pragma unroll
        for (int j2 = 0; j2 < 4; ++j2) acc[i][j2] += aa[i] * bb[j2];
    }
    __syncthreads();
  }
  float* Pb = P + (((size_t)bj) << 18);
#pragma unroll
  for (int i = 0; i < 4; ++i)
#pragma unroll
    for (int j2 = 0; j2 < 4; ++j2)
      Pb[(size_t)(be + (tm << 2) + i) * E_DIM + bep + (tn << 2) + j2] = acc[i][j2];
}

// ---------------- per-chunk ksum_j[e] ----------------
__global__ void ksum_k(const float* __restrict__ k, float* __restrict__ ks) {
  const int bj = blockIdx.x;
  const int b = bj >> 3, j = bj & 7;
  const int e = threadIdx.x;  // 512
  const float* kp = k + (((size_t)(b * S_LEN + j * CHK)) << 9) + e;
  float s = 0.f;
  for (int t = 0; t < CHK; ++t) s += kp[((size_t)t) << 9];
  ks[(bj << 9) + e] = s;
}

// ---------------- pass B: in-place exclusive prefix over chunk dim ----------------
__global__ void prefix_kv(float* __restrict__ P) {
  const size_t idx = (size_t)blockIdx.x * 256 + threadIdx.x;  // < B*E*E
  const int b = (int)(idx >> 18);
  const size_t r = idx & ((1u << 18) - 1);
  float acc = 0.f;
#pragma unroll
  for (int j = 0; j < NCHK; ++j) {
    float* p = P + (((size_t)(b * NCHK + j)) << 18) + r;
    float t = *p;
    *p = acc;
    acc += t;
  }
}
__global__ void prefix_ks(float* __restrict__ ks) {
  const int idx = blockIdx.x * 256 + threadIdx.x;  // < B*E
  const int b = idx >> 9, r = idx & 511;
  float acc = 0.f;
#pragma unroll
  for (int j = 0; j < NCHK; ++j) {
    float* p = ks + ((b * NCHK + j) << 9) + r;
    float t = *p;
    *p = acc;
    acc += t;
  }
}

// ---------------- pass C1: intra-chunk masked scores ----------------
__global__ __launch_bounds__(256) void intra_scores(const float* __restrict__ q,
                                                    const float* __restrict__ k,
                                                    float* __restrict__ Sc) {
  const int bj = blockIdx.z;
  const int b = bj >> 3, j = bj & 7;
  const int bs = blockIdx.x << 6, bt = blockIdx.y << 6;
  const int tid = threadIdx.x, tm = tid >> 4, tn = tid & 15;
  float* sc = Sc + (((size_t)bj) << 16);  // C*C = 65536
  if (bt > bs + 63) {                     // fully masked tile -> zeros
    const float4 z = make_float4(0.f, 0.f, 0.f, 0.f);
#pragma unroll
    for (int i = 0; i < 4; ++i)
      *(float4*)(sc + (size_t)(bs + (tm << 2) + i) * CHK + bt + (tn << 2)) = z;
    return;
  }
  __shared__ float Qs[16][64], Ks[16][64];
  const int lr = tid >> 2, lc = (tid & 3) << 2;
  float acc[4][4] = {{0.f}};
  const size_t qbase = ((size_t)(b * S_LEN + j * CHK + bs)) << 9;
  const size_t kbase = ((size_t)(b * S_LEN + j * CHK + bt)) << 9;
  for (int e0 = 0; e0 < E_DIM; e0 += 16) {
    float4 av = *(const float4*)(q + qbase + (((size_t)lr) << 9) + e0 + lc);
    TSTORE(Qs, av, lr, lc);
    float4 bv = *(const float4*)(k + kbase + (((size_t)lr) << 9) + e0 + lc);
    TSTORE(Ks, bv, lr, lc);
    __syncthreads();
#pragma unroll
    for (int kk = 0; kk < 16; ++kk) {
      const float4 a4 = *(const float4*)&Qs[kk][tm << 2];
      const float4 b4 = *(const float4*)&Ks[kk][tn << 2];
      const float aa[4] = {a4.x, a4.y, a4.z, a4.w};
      const float bb[4] = {b4.x, b4.y, b4.z, b4.w};
#pragma unroll
      for (int i = 0; i < 4; ++i)
#pragma unroll
        for (int j2 = 0; j2 < 4; ++j2) acc[i][j2] += aa[i] * bb[j2];
    }
    __syncthreads();
  }
#pragma unroll
  for (int i = 0; i < 4; ++i)
#pragma unroll
    for (int j2 = 0; j2 < 4; ++j2) {
      const int sl = bs + (tm << 2) + i, tl = bt + (tn << 2) + j2;
      sc[(size_t)sl * CHK + tl] = (tl <= sl) ? acc[i][j2] : 0.f;
    }
}

// ---------------- den[b,s] = rowsum(intra scores) + q . ksum_prefix ----------------
__global__ void den_k(const float* __restrict__ Sc, const float* __restrict__ q,
                      const float* __restrict__ ks, float* __restrict__ den) {
  const int bj = blockIdx.x;
  const int b = bj >> 3, j = bj & 7;
  const int sl = threadIdx.x;  // 256
  const float* srow = Sc + (((size_t)bj) << 16) + (size_t)sl * CHK;
  float d = 0.f;
  for (int t = 0; t < CHK; ++t) d += srow[t];
  const float* qr = q + (((size_t)(b * S_LEN + j * CHK + sl)) << 9);
  const float* kp = ks + (bj << 9);
  for (int e = 0; e < E_DIM; ++e) d += qr[e] * kp[e];
  den[b * S_LEN + j * CHK + sl] = d;
}

// ---------------- pass C2: out = (scores@v + q@P) / (den+eps) ----------------
__global__ __launch_bounds__(256) void attn_combine(
    const float* __restrict__ Sc, const float* __restrict__ v,
    const float* __restrict__ q, const float* __restrict__ P,
    const float* __restrict__ den, float* __restrict__ out) {
  const int bj = blockIdx.z;
  const int b = bj >> 3, j = bj & 7;
  const int bs = blockIdx.x << 6, be = blockIdx.y << 6;
  const int tid = threadIdx.x, tm = tid >> 4, tn = tid & 15;
  __shared__ float As[16][64], Bs[16][64];
  float acc[4][4] = {{0.f}};
  const size_t rbase = (size_t)(b * S_LEN + j * CHK);
  {  // scores @ v   (K-dim = t)
    const int lrA = tid >> 2, lcA = (tid & 3) << 2;
    const int lrB = tid >> 4, lcB = (tid & 15) << 2;
    const float* sc = Sc + (((size_t)bj) << 16);
    for (int t0 = 0; t0 < CHK; t0 += 16) {
      float4 av = *(const float4*)(sc + (size_t)(bs + lrA) * CHK + t0 + lcA);
      TSTORE(As, av, lrA, lcA);
      *(float4*)&Bs[lrB][lcB] =
          *(const float4*)(v + ((rbase + t0 + lrB) << 9) + be + lcB);
      __syncthreads();
#pragma unroll
      for (int kk = 0; kk < 16; ++kk) {
        const float4 a4 = *(const float4*)&As[kk][tm << 2];
        const float4 b4 = *(const float4*)&Bs[kk][tn << 2];
        const float aa[4] = {a4.x, a4.y, a4.z, a4.w};
        const float bb[4] = {b4.x, b4.y, b4.z, b4.w};
#pragma unroll
        for (int i = 0; i < 4; ++i)
#pragma unroll
          for (int j2 = 0; j2 < 4; ++j2) acc[i][j2] += aa[i] * bb[j2];
      }
      __syncthreads();
    }
  }
  {  // q @ P   (K-dim = e)
    const int lrA = tid >> 2, lcA = (tid & 3) << 2;
    const int lrB = tid >> 4, lcB = (tid & 15) << 2;
    const float* Pb = P + (((size_t)bj) << 18);
    for (int e0 = 0; e0 < E_DIM; e0 += 16) {
      float4 av = *(const float4*)(q + ((rbase + bs + lrA) << 9) + e0 + lcA);
      TSTORE(As, av, lrA, lcA);
      *(float4*)&Bs[lrB][lcB] =
          *(const float4*)(Pb + ((size_t)(e0 + lrB) << 9) + be + lcB);
      __syncthreads();
#pragma unroll
      for (int kk = 0; kk < 16; ++kk) {
        const float4 a4 = *(const float4*)&As[kk][tm << 2];
        const float4 b4 = *(const float4*)&Bs[kk][tn << 2];
        const float aa[4] = {a4.x, a4.y, a4.z, a4.w};
        const float bb[4] = {b4.x, b4.y, b4.z, b4.w};
#pragma unroll
        for (int i = 0; i < 4; ++i)
#pragma unroll
          for (int j2 = 0; j2 < 4; ++j2) acc[i][j2] += aa[i] * bb[j2];
      }
      __syncthreads();
    }
  }
#pragma unroll
  for (int i = 0; i < 4; ++i) {
    const int sl = bs + (tm << 2) + i;
    const float d = den[rbase + sl] + 1e-6f;
    const float inv = 1.f / d;
#pragma unroll
    for (int j2 = 0; j2 < 4; ++j2)
      out[((rbase + sl) << 9) + be + (tn << 2) + j2] = acc[i][j2] * inv;
  }
}

// ---------------- output projection: out[b,o,s] = lat[b,s,:] . out_W[o,:] + out_b[o]
__global__ __launch_bounds__(256) void out_proj(const float* __restrict__ lat,
                                                const float* __restrict__ W,
                                                const float* __restrict__ bias,
                                                float* __restrict__ out) {
  const int b = blockIdx.z, bs = blockIdx.x << 6;
  const int tid = threadIdx.x, tm = tid >> 4, tn = tid & 15;
  const int lr = tid >> 2, lc = (tid & 3) << 2;
  __shared__ float As[16][64], Ws[16][64];
  float acc[4][4] = {{0.f}};
  for (int k0 = 0; k0 < E_DIM; k0 += 16) {
    float4 av =
        *(const float4*)(lat + (((size_t)(b * S_LEN + bs + lr)) << 9) + k0 + lc);
    TSTORE(As, av, lr, lc);
    float4 wv = *(const float4*)(W + (((size_t)lr) << 9) + k0 + lc);
    TSTORE(Ws, wv, lr, lc);
    __syncthreads();
#pragma unroll
    for (int kk = 0; kk < 16; ++kk) {
      const float4 a4 = *(const float4*)&As[kk][tm << 2];
      const float4 b4 = *(const float4*)&Ws[kk][tn << 2];
      const float aa[4] = {a4.x, a4.y, a4.z, a4.w};
      const float bb[4] = {b4.x, b4.y, b4.z, b4.w};
#pragma unroll
      for (int i = 0; i < 4; ++i)
#pragma unroll
        for (int j2 = 0; j2 < 4; ++j2) acc[i][j2] += aa[i] * bb[j2];
    }
    __syncthreads();
  }
#pragma unroll
  for (int i = 0; i < 4; ++i)
#pragma unroll
    for (int j2 = 0; j2 < 4; ++j2) {
      const int o = (tn << 2) + j2, sl = bs + (tm << 2) + i;
      out[(((size_t)(b * COUT_D + o)) << 11) + sl] = acc[i][j2] + bias[o];
    }
}

// ---------------- host launcher ----------------
extern "C" void kernel_launch(void* const* d_in, const int* in_sizes, int n_in,
                              void* d_out, int out_size, void* d_ws,
                              size_t ws_size, hipStream_t stream) {
  const float* x = (const float*)d_in[0];
  const float* in_W = (const float*)d_in[1];
  const float* in_b = (const float*)d_in[2];
  const float* cc_W = (const float*)d_in[3];
  const float* cc_b = (const float*)d_in[4];
  const float* ln1g = (const float*)d_in[5];
  const float* ln1b = (const float*)d_in[6];
  const float* ln2g = (const float*)d_in[7];
  const float* ln2b = (const float*)d_in[8];
  const float* Wq = (const float*)d_in[9];
  const float* bq = (const float*)d_in[10];
  const float* Wk = (const float*)d_in[11];
  const float* bk = (const float*)d_in[12];
  const float* Wv = (const float*)d_in[13];
  const float* bv = (const float*)d_in[14];
  const float* Wo = (const float*)d_in[15];
  const float* bo = (const float*)d_in[16];
  const float* c1W = (const float*)d_in[17];
  const float* c1b = (const float*)d_in[18];
  const float* c2W = (const float*)d_in[19];
  const float* c2b = (const float*)d_in[20];
  const float* oW = (const float*)d_in[21];
  const float* ob = (const float*)d_in[22];
  float* out = (float*)d_out;

  float* ws = (float*)d_ws;
  size_t off = 0;
  auto alloc = [&](size_t n) {
    float* p = ws + off;
    off += n;
    return p;
  };
  const size_t NE = (size_t)ROWS * E_DIM;  // 4M floats
  float* lat = alloc(NE);
  float* h = alloc(NE);
  float* q = alloc(NE);
  float* k = alloc(NE);
  float* v = alloc(NE);
  float* t2 = alloc(NE);
  float* xT = alloc((size_t)ROWS * CIN_D);
  float* w0 = alloc((size_t)E_DIM * E_DIM);
  float* w1 = alloc((size_t)E_DIM * E_DIM);
  float* w2 = alloc((size_t)E_DIM * E_DIM);
  float* P = alloc((size_t)B_SZ * NCHK * E_DIM * E_DIM);
  float* ks = alloc((size_t)B_SZ * NCHK * E_DIM);
  float* Sc = alloc((size_t)B_SZ * NCHK * CHK * CHK);
  float* den = alloc((size_t)B_SZ * S_LEN);

  const dim3 blk(256);
  const dim3 ggrid(ROWS / 64, E_DIM / 64);

  repack_ccw<<<dim3(E_DIM * E_DIM / 256), blk, 0, stream>>>(cc_W, w0, w1, w2);
  transpose_x<<<dim3(S_LEN / 64, 1, B_SZ), blk, 0, stream>>>(x, xT);
  gemm_nt<0, 0, false><<<ggrid, blk, 0, stream>>>(xT, in_W, in_b, t2, ROWS,
                                                  E_DIM, CIN_D, 0);
  gemm_nt<0, 0, true><<<ggrid, blk, 0, stream>>>(t2, w0, cc_b, lat, ROWS, E_DIM,
                                                 E_DIM, -2);
  gemm_nt<1, 0, true><<<ggrid, blk, 0, stream>>>(t2, w1, nullptr, lat, ROWS,
                                                 E_DIM, E_DIM, -1);
  gemm_nt<1, 0, true><<<ggrid, blk, 0, stream>>>(t2, w2, nullptr, lat, ROWS,
                                                 E_DIM, E_DIM, 0);

  for (int i = 0; i < L_NUM; ++i) {
    const size_t wOff = (size_t)i * E_DIM * E_DIM;
    const size_t bOff = (size_t)i * E_DIM;
    layernorm_k<<<ROWS, blk, 0, stream>>>(lat, ln1g + bOff, ln1b + bOff, h);
    gemm_nt<0, 1, false><<<ggrid, blk, 0, stream>>>(h, Wq + wOff, bq + bOff, q,
                                                    ROWS, E_DIM, E_DIM, 0);
    gemm_nt<0, 1, false><<<ggrid, blk, 0, stream>>>(h, Wk + wOff, bk + bOff, k,
                                                    ROWS, E_DIM, E_DIM, 0);
    gemm_nt<0, 0, false><<<ggrid, blk, 0, stream>>>(h, Wv + wOff, bv + bOff, v,
                                                    ROWS, E_DIM, E_DIM, 0);
    chunk_kv<<<dim3(8, 8, B_SZ * NCHK), blk, 0, stream>>>(k, v, P);
    ksum_k<<<dim3(B_SZ * NCHK), dim3(512), 0, stream>>>(k, ks);
    prefix_kv<<<dim3(B_SZ * E_DIM * E_DIM / 256), blk, 0, stream>>>(P);
    prefix_ks<<<dim3(B_SZ * E_DIM / 256), blk, 0, stream>>>(ks);
    intra_scores<<<dim3(4, 4, B_SZ * NCHK), blk, 0, stream>>>(q, k, Sc);
    den_k<<<dim3(B_SZ * NCHK), dim3(256), 0, stream>>>(Sc, q, ks, den);
    attn_combine<<<dim3(4, 8, B_SZ * NCHK), blk, 0, stream>>>(Sc, v, q, P, den,
                                                              t2);
    gemm_nt<1, 0, false><<<ggrid, blk, 0, stream>>>(t2, Wo + wOff, bo + bOff,
                                                    lat, ROWS, E_DIM, E_DIM, 0);
    layernorm_k<<<ROWS, blk, 0, stream>>>(lat, ln2g + bOff, ln2b + bOff, h);
    gemm_nt<0, 2, false><<<ggrid, blk, 0, stream>>>(h, c1W + wOff, c1b + bOff,
                                                    t2, ROWS, E_DIM, E_DIM, 0);
    gemm_nt<1, 0, false><<<ggrid, blk, 0, stream>>>(t2, c2W + wOff, c2b + bOff,
                                                    lat, ROWS, E_DIM, E_DIM, 0);
  }
  out_proj<<<dim3(S_LEN / 64, 1, B_SZ), blk, 0, stream>>>(lat, oW, ob, out);
}

// Round 2
// 1027.522 us; speedup vs baseline: 2.9154x; 2.9154x over previous
//
#include <hip/hip_runtime.h>
#include <hip/hip_bf16.h>
#include <cmath>

#define S_LEN 2048
#define E_DIM 512
#define B_SZ 4
#define CIN_D 64
#define COUT_D 64
#define L_NUM 4
#define CHK 256
#define NCHK 8
#define ROWS (B_SZ * S_LEN)  // 8192
#define PADR 2050            // padded rows per batch for causal conv

typedef __attribute__((ext_vector_type(8))) short short8;
typedef __attribute__((ext_vector_type(4))) float f32x4;
typedef unsigned short ushort_t;

__device__ __forceinline__ ushort_t f2b(float v) {
  __hip_bfloat16 t = __float2bfloat16(v);
  return __builtin_bit_cast(ushort_t, t);
}
__device__ __forceinline__ float b2f(ushort_t u) {
  return __builtin_bit_cast(float, ((unsigned)u) << 16);
}

__device__ __forceinline__ void gload16(const void* g, void* l) {
  __builtin_amdgcn_global_load_lds((const __attribute__((address_space(1))) void*)g,
                                   (__attribute__((address_space(3))) void*)l, 16, 0, 0);
}

// ======================= universal bf16 MFMA GEMM =======================
// C[m,n] = act(sum_k A[arow(m),k+acol] * B[brow(n),k+bcol] + bias) (+Cf) (*1/den)
// 128x128 tile, BK=64, 4 waves (2x2), 4x4 fragments of 16x16x32 per wave.
struct GemmP {
  const ushort_t* A; const ushort_t* B; const float* bias;
  float* Cf; ushort_t* Cb; const float* den;
  int K, lda, ldb, ldc;
  int aZrow, aZcol, bZrow, bZcol, cZrow, rowOffA;
  const ushort_t* A2; const ushort_t* B2;
  int K2, lda2, ldb2, a2Zrow, b2Zrow;
};

__device__ __forceinline__ void mma_phase(const ushort_t* A, const ushort_t* B,
                                          int K, int lda, int ldb, int arow0,
                                          int acol0, int brow0, int bcol0,
                                          char* smem, int tid, f32x4 acc[4][4]) {
  const int lane = tid & 63;
  const int w = tid >> 6;
  const int wr = (w >> 1) << 6, wc = (w & 1) << 6;
  const int l15 = lane & 15, l4 = lane >> 4;
  for (int kt = 0; kt < (K >> 6); ++kt) {
#pragma unroll
    for (int r = 0; r < 4; ++r) {
      const int f = (r << 12) + (tid << 4);
      const int row = f >> 7, c16 = (f >> 4) & 7;
      const int sw = (c16 ^ (row & 7)) << 3;  // element offset of 16B chunk
      const ushort_t* ga = A + (size_t)(arow0 + row) * lda + acol0 + (kt << 6) + sw;
      gload16(ga, smem + f);
      const ushort_t* gb = B + (size_t)(brow0 + row) * ldb + bcol0 + (kt << 6) + sw;
      gload16(gb, smem + 16384 + f);
    }
    __syncthreads();
#pragma unroll
    for (int kk = 0; kk < 2; ++kk) {
      short8 af[4], bfv[4];
#pragma unroll
      for (int m = 0; m < 4; ++m) {
        const int rt = wr + (m << 4) + l15;
        af[m] = *(const short8*)(smem + rt * 128 +
                                 (((kk << 6) + (l4 << 4)) ^ ((rt & 7) << 4)));
      }
#pragma unroll
      for (int n = 0; n < 4; ++n) {
        const int rt = wc + (n << 4) + l15;
        bfv[n] = *(const short8*)(smem + 16384 + rt * 128 +
                                  (((kk << 6) + (l4 << 4)) ^ ((rt & 7) << 4)));
      }
#pragma unroll
      for (int m = 0; m < 4; ++m)
#pragma unroll
        for (int n = 0; n < 4; ++n)
          acc[m][n] = __builtin_amdgcn_mfma_f32_16x16x32_bf16(af[m], bfv[n],
                                                              acc[m][n], 0, 0, 0);
    }
    __syncthreads();
  }
}

template <int ACT, bool READC, bool WRITEF, bool WRITEB, bool PADA, bool PADC,
          bool BIASROW, bool TRIMASK, bool SKIPUP, bool DIVDEN, bool TWOPH>
__global__ __launch_bounds__(256) void gemm_mfma(GemmP p) {
  __shared__ __align__(16) char smem[32768];
  const int tid = threadIdx.x;
  const int bm = blockIdx.x << 7, bn = blockIdx.y << 7, z = blockIdx.z;
  const int lane = tid & 63, w = tid >> 6;
  const int wr = (w >> 1) << 6, wc = (w & 1) << 6;
  const int l15 = lane & 15, l4 = lane >> 4;

  if (SKIPUP && bn >= bm + 128) {  // fully-masked tile: zero-fill Cb
#pragma unroll
    for (int m = 0; m < 4; ++m)
#pragma unroll
      for (int j = 0; j < 4; ++j) {
        const int rloc = bm + wr + (m << 4) + (l4 << 2) + j;
        const size_t crow = (size_t)p.cZrow * z + rloc;
#pragma unroll
        for (int n = 0; n < 4; ++n)
          p.Cb[crow * p.ldc + bn + wc + (n << 4) + l15] = 0;
      }
    return;
  }

  f32x4 acc[4][4];
#pragma unroll
  for (int m = 0; m < 4; ++m)
#pragma unroll
    for (int n = 0; n < 4; ++n)
#pragma unroll
      for (int j = 0; j < 4; ++j) acc[m][n][j] = 0.f;

  int arow0 = bm + p.aZrow * z;
  if (PADA) arow0 = bm + ((bm >> 11) << 1) + p.rowOffA;
  mma_phase(p.A, p.B, p.K, p.lda, p.ldb, arow0, p.aZcol * z, bn + p.bZrow * z,
            p.bZcol * z, smem, tid, acc);
  if (TWOPH)
    mma_phase(p.A2, p.B2, p.K2, p.lda2, p.ldb2, bm + p.a2Zrow * z, 0,
              bn + p.b2Zrow * z, 0, smem, tid, acc);

  float bcol[4];
  if (p.bias && !BIASROW) {
#pragma unroll
    for (int n = 0; n < 4; ++n) bcol[n] = p.bias[bn + wc + (n << 4) + l15];
  }
  int crow_base = bm;
  if (PADC) crow_base = bm + ((bm >> 11) << 1) + 2;
#pragma unroll
  for (int m = 0; m < 4; ++m) {
#pragma unroll
    for (int j = 0; j < 4; ++j) {
      const int rloc = wr + (m << 4) + (l4 << 2) + j;
      const size_t crow = (size_t)p.cZrow * z + crow_base + rloc;
      float inv = 1.f;
      if (DIVDEN) inv = 1.f / (p.den[crow] + 1e-6f);
      float brbias = 0.f;
      if (BIASROW && p.bias) brbias = p.bias[bm + rloc];
#pragma unroll
      for (int n = 0; n < 4; ++n) {
        const int col = bn + wc + (n << 4) + l15;
        float v = acc[m][n][j];
        if (p.bias) v += BIASROW ? brbias : bcol[n];
        if (ACT == 1) v = v > 0.f ? v + 1.f : __expf(v);
        if (ACT == 2) v = 0.5f * v * (1.f + erff(v * 0.70710678118654752f));
        if (TRIMASK) {
          if (col > bm + rloc) v = 0.f;  // local chunk coords
        }
        const size_t cidx = crow * p.ldc + col;
        if (READC) v += p.Cf[cidx];
        if (DIVDEN) v *= inv;
        if (WRITEF) p.Cf[cidx] = v;
        if (WRITEB) p.Cb[cidx] = f2b(v);
      }
    }
  }
}

// ======================= small fp32 helper kernels =======================

__global__ __launch_bounds__(256) void transpose_x(const float* __restrict__ x,
                                                   ushort_t* __restrict__ xT) {
  __shared__ float t[64][65];
  const int b = blockIdx.z, s0 = blockIdx.x << 6, tid = threadIdx.x;
#pragma unroll
  for (int i = 0; i < 16; ++i) {
    int idx = tid + (i << 8);
    int c = idx >> 6, s = idx & 63;
    t[c][s] = x[(((size_t)(b * CIN_D + c)) << 11) + s0 + s];
  }
  __syncthreads();
#pragma unroll
  for (int i = 0; i < 16; ++i) {
    int idx = tid + (i << 8);
    int s = idx >> 6, c = idx & 63;
    xT[(((size_t)(b * S_LEN + s0 + s)) << 6) + c] = f2b(t[c][s]);
  }
}

__global__ void cvt_bf(const float* __restrict__ s, ushort_t* __restrict__ d, int n) {
  int i = blockIdx.x * 256 + threadIdx.x;
  if (i < n) d[i] = f2b(s[i]);
}

__global__ void repack_ccw(const float* __restrict__ cw, ushort_t* __restrict__ w0,
                           ushort_t* __restrict__ w1, ushort_t* __restrict__ w2) {
  const int i = blockIdx.x * 256 + threadIdx.x;  // < E*E
  w0[i] = f2b(cw[3 * i + 0]);
  w1[i] = f2b(cw[3 * i + 1]);
  w2[i] = f2b(cw[3 * i + 2]);
}

__global__ void zpad(ushort_t* __restrict__ t2pad) {
  int i = blockIdx.x * 256 + threadIdx.x;  // 4096
  int b = i >> 10, r = i & 1023;
  t2pad[(size_t)(b * PADR) * E_DIM + r] = 0;
}

__global__ __launch_bounds__(256) void layernorm_k(const float* __restrict__ x,
                                                   const float* __restrict__ g,
                                                   const float* __restrict__ bb,
                                                   ushort_t* __restrict__ y) {
  const int row = blockIdx.x, tid = threadIdx.x;
  const float2 v = *(const float2*)(x + (((size_t)row) << 9) + (tid << 1));
  float s = v.x + v.y, q = v.x * v.x + v.y * v.y;
#pragma unroll
  for (int off = 32; off; off >>= 1) {
    s += __shfl_down(s, off);
    q += __shfl_down(q, off);
  }
  __shared__ float rs[4], rq[4], mv[2];
  const int wid = tid >> 6, lane = tid & 63;
  if (lane == 0) {
    rs[wid] = s;
    rq[wid] = q;
  }
  __syncthreads();
  if (tid == 0) {
    float S_ = rs[0] + rs[1] + rs[2] + rs[3];
    float Q_ = rq[0] + rq[1] + rq[2] + rq[3];
    float m = S_ * (1.f / 512.f);
    float var = Q_ * (1.f / 512.f) - m * m;
    mv[0] = m;
    mv[1] = rsqrtf(var + 1e-5f);
  }
  __syncthreads();
  const float m = mv[0], r = mv[1];
  const int c = tid << 1;
  float ox = (v.x - m) * r * g[c] + bb[c];
  float oy = (v.y - m) * r * g[c + 1] + bb[c + 1];
  unsigned pk = ((unsigned)f2b(oy) << 16) | f2b(ox);
  *(unsigned*)(y + (((size_t)row) << 9) + c) = pk;
}

// ksum[z][e] = sum_t kT[e][z*256+t]
__global__ void ksum_k(const ushort_t* __restrict__ kT, float* __restrict__ ks) {
  const int z = blockIdx.x, e = threadIdx.x;  // 512 threads
  const ushort_t* p = kT + (size_t)e * ROWS + z * CHK;
  float s = 0.f;
  for (int t = 0; t < CHK; ++t) s += b2f(p[t]);
  ks[(z << 9) + e] = s;
}

__global__ void prefix_ks(float* __restrict__ ks) {
  const int idx = blockIdx.x * 256 + threadIdx.x;  // < B*E
  const int b = idx >> 9, e = idx & 511;
  float acc = 0.f;
#pragma unroll
  for (int j = 0; j < NCHK; ++j) {
    float* p = ks + ((b * NCHK + j) << 9) + e;
    float t = *p;
    *p = acc;
    acc += t;
  }
}

// exclusive prefix over chunks of P (fp32) -> PTb (bf16)
__global__ void prefix_kv(const float* __restrict__ P, ushort_t* __restrict__ PTb) {
  const size_t idx = (size_t)blockIdx.x * 256 + threadIdx.x;  // < B*E*E
  const int b = (int)(idx >> 18);
  const size_t r = idx & ((1u << 18) - 1);
  float acc = 0.f;
#pragma unroll
  for (int j = 0; j < NCHK; ++j) {
    const size_t o = (((size_t)(b * NCHK + j)) << 18) + r;
    PTb[o] = f2b(acc);
    acc += P[o];
  }
}

// den[row] = rowsum(Sc[row]) + q[row] . ks[chunk]
__global__ __launch_bounds__(256) void den_k(const ushort_t* __restrict__ Sc,
                                             const ushort_t* __restrict__ q,
                                             const float* __restrict__ ks,
                                             float* __restrict__ den) {
  const int wid = threadIdx.x >> 6, lane = threadIdx.x & 63;
  const int row = blockIdx.x * 4 + wid;  // < 8192
  const int z = row >> 8, sl = row & 255;
  const ushort_t* sr = Sc + (((size_t)z) << 16) + (size_t)sl * CHK;
  float s = 0.f;
  for (int t = lane; t < CHK; t += 64) s += b2f(sr[t]);
  const ushort_t* qr = q + (((size_t)row) << 9);
  const float* kp = ks + (z << 9);
  for (int e = lane; e < E_DIM; e += 64) s += b2f(qr[e]) * kp[e];
#pragma unroll
  for (int off = 32; off; off >>= 1) s += __shfl_down(s, off);
  if (lane == 0) den[row] = s;
}

__global__ __launch_bounds__(256) void out_proj(const float* __restrict__ lat,
                                                const float* __restrict__ W,
                                                const float* __restrict__ bias,
                                                float* __restrict__ out) {
  const int b = blockIdx.z, bs = blockIdx.x << 6;
  const int tid = threadIdx.x, tm = tid >> 4, tn = tid & 15;
  const int lr = tid >> 2, lc = (tid & 3) << 2;
  __shared__ float As[16][64], Ws[16][64];
  float acc[4][4] = {{0.f}};
  for (int k0 = 0; k0 < E_DIM; k0 += 16) {
    float4 av =
        *(const float4*)(lat + (((size_t)(b * S_LEN + bs + lr)) << 9) + k0 + lc);
    As[lc + 0][lr] = av.x; As[lc + 1][lr] = av.y;
    As[lc + 2][lr] = av.z; As[lc + 3][lr] = av.w;
    float4 wv = *(const float4*)(W + (((size_t)lr) << 9) + k0 + lc);
    Ws[lc + 0][lr] = wv.x; Ws[lc + 1][lr] = wv.y;
    Ws[lc + 2][lr] = wv.z; Ws[lc + 3][lr] = wv.w;
    __syncthreads();
#pragma unroll
    for (int kk = 0; kk < 16; ++kk) {
      const float4 a4 = *(const float4*)&As[kk][tm << 2];
      const float4 b4 = *(const float4*)&Ws[kk][tn << 2];
      const float aa[4] = {a4.x, a4.y, a4.z, a4.w};
      const float bb[4] = {b4.x, b4.y, b4.z, b4.w};
#pragma unroll
      for (int i = 0; i < 4; ++i)
#pragma unroll
        for (int j2 = 0; j2 < 4; ++j2) acc[i][j2] += aa[i] * bb[j2];
    }
    __syncthreads();
  }
#pragma unroll
  for (int i = 0; i < 4; ++i)
#pragma unroll
    for (int j2 = 0; j2 < 4; ++j2) {
      const int o = (tn << 2) + j2, sl = bs + (tm << 2) + i;
      out[(((size_t)(b * COUT_D + o)) << 11) + sl] = acc[i][j2] + bias[o];
    }
}

// ======================= host launcher =======================
extern "C" void kernel_launch(void* const* d_in, const int* in_sizes, int n_in,
                              void* d_out, int out_size, void* d_ws,
                              size_t ws_size, hipStream_t stream) {
  const float* x = (const float*)d_in[0];
  const float* in_W = (const float*)d_in[1];
  const float* in_b = (const float*)d_in[2];
  const float* cc_W = (const float*)d_in[3];
  const float* cc_b = (const float*)d_in[4];
  const float* ln1g = (const float*)d_in[5];
  const float* ln1b = (const float*)d_in[6];
  const float* ln2g = (const float*)d_in[7];
  const float* ln2b = (const float*)d_in[8];
  const float* Wq = (const float*)d_in[9];
  const float* bq = (const float*)d_in[10];
  const float* Wk = (const float*)d_in[11];
  const float* bk = (const float*)d_in[12];
  const float* Wv = (const float*)d_in[13];
  const float* bv = (const float*)d_in[14];
  const float* Wo = (const float*)d_in[15];
  const float* bo = (const float*)d_in[16];
  const float* c1W = (const float*)d_in[17];
  const float* c1b = (const float*)d_in[18];
  const float* c2W = (const float*)d_in[19];
  const float* c2b = (const float*)d_in[20];
  const float* oW = (const float*)d_in[21];
  const float* ob = (const float*)d_in[22];
  float* out = (float*)d_out;

  const size_t NE = (size_t)ROWS * E_DIM;  // 4194304
  float* lat = (float*)d_ws;
  float* P = lat + NE;          // 8388608 f32
  float* ks = P + 8388608;      // 16384
  float* den = ks + 16384;      // 8192
  ushort_t* u = (ushort_t*)(den + 8192);
  ushort_t* xT = u;     u += (size_t)ROWS * CIN_D;
  ushort_t* t2pad = u;  u += (size_t)B_SZ * PADR * E_DIM;
  ushort_t* h = u;      u += NE;
  ushort_t* q = u;      u += NE;
  ushort_t* kbuf = u;   u += NE;
  ushort_t* kT = u;     u += NE;
  ushort_t* vT = u;     u += NE;
  ushort_t* PTb = u;    u += 8388608;
  ushort_t* winb = u;   u += 32768;
  ushort_t* w0b = u;    u += 262144;
  ushort_t* w1b = u;    u += 262144;
  ushort_t* w2b = u;    u += 262144;
  ushort_t* wqb = u;    u += 1048576;
  ushort_t* wkb = u;    u += 1048576;
  ushort_t* wvb = u;    u += 1048576;
  ushort_t* wob = u;    u += 1048576;
  ushort_t* wc1 = u;    u += 1048576;
  ushort_t* wc2 = u;    u += 1048576;
  ushort_t* Sc = (ushort_t*)P;  // alias: P dead after prefix, Sc written after
  ushort_t* t2b = kbuf;         // alias: k dead after intra_scores

  const dim3 blk(256);
  // weight conversions
  cvt_bf<<<dim3(128), blk, 0, stream>>>(in_W, winb, 32768);
  repack_ccw<<<dim3(1024), blk, 0, stream>>>(cc_W, w0b, w1b, w2b);
  cvt_bf<<<dim3(4096), blk, 0, stream>>>(Wq, wqb, 1048576);
  cvt_bf<<<dim3(4096), blk, 0, stream>>>(Wk, wkb, 1048576);
  cvt_bf<<<dim3(4096), blk, 0, stream>>>(Wv, wvb, 1048576);
  cvt_bf<<<dim3(4096), blk, 0, stream>>>(Wo, wob, 1048576);
  cvt_bf<<<dim3(4096), blk, 0, stream>>>(c1W, wc1, 1048576);
  cvt_bf<<<dim3(4096), blk, 0, stream>>>(c2W, wc2, 1048576);
  transpose_x<<<dim3(S_LEN / 64, 1, B_SZ), blk, 0, stream>>>(x, xT);
  zpad<<<dim3(16), blk, 0, stream>>>(t2pad);

  GemmP p;
  auto clr = [&]() {
    p = GemmP{};
    p.lda = E_DIM; p.ldb = E_DIM; p.ldc = E_DIM;
  };

  // input projection -> padded bf16 latent
  clr(); p.A = xT; p.B = winb; p.bias = in_b; p.Cb = t2pad;
  p.K = 64; p.lda = 64; p.ldb = 64;
  gemm_mfma<0,0,0,1,0,1,0,0,0,0,0><<<dim3(64,4), blk, 0, stream>>>(p);
  // causal conv = 3 tap GEMMs into fp32 lat
  clr(); p.A = t2pad; p.B = w0b; p.bias = cc_b; p.Cf = lat; p.K = E_DIM; p.rowOffA = 0;
  gemm_mfma<0,0,1,0,1,0,0,0,0,0,0><<<dim3(64,4), blk, 0, stream>>>(p);
  clr(); p.A = t2pad; p.B = w1b; p.Cf = lat; p.K = E_DIM; p.rowOffA = 1;
  gemm_mfma<0,1,1,0,1,0,0,0,0,0,0><<<dim3(64,4), blk, 0, stream>>>(p);
  p.B = w2b; p.rowOffA = 2;
  gemm_mfma<0,1,1,0,1,0,0,0,0,0,0><<<dim3(64,4), blk, 0, stream>>>(p);

  for (int i = 0; i < L_NUM; ++i) {
    const size_t wOff = (size_t)i * E_DIM * E_DIM;
    const size_t bOff = (size_t)i * E_DIM;
    layernorm_k<<<dim3(ROWS), blk, 0, stream>>>(lat, ln1g + bOff, ln1b + bOff, h);
    // q, k (phi fused, bf16 out)
    clr(); p.A = h; p.B = wqb + wOff; p.bias = bq + bOff; p.Cb = q; p.K = E_DIM;
    gemm_mfma<1,0,0,1,0,0,0,0,0,0,0><<<dim3(64,4), blk, 0, stream>>>(p);
    p.B = wkb + wOff; p.bias = bk + bOff; p.Cb = kbuf;
    gemm_mfma<1,0,0,1,0,0,0,0,0,0,0><<<dim3(64,4), blk, 0, stream>>>(p);
    // kT, vT via swapped operands (bias per ROW)
    clr(); p.A = wkb + wOff; p.B = h; p.bias = bk + bOff; p.Cb = kT;
    p.K = E_DIM; p.ldc = ROWS;
    gemm_mfma<1,0,0,1,0,0,1,0,0,0,0><<<dim3(4,64), blk, 0, stream>>>(p);
    clr(); p.A = wvb + wOff; p.B = h; p.bias = bv + bOff; p.Cb = vT;
    p.K = E_DIM; p.ldc = ROWS;
    gemm_mfma<0,0,0,1,0,0,1,0,0,0,0><<<dim3(4,64), blk, 0, stream>>>(p);
    // per-chunk PT[e'][e] = sum_t vT[e',t] kT[e,t]
    clr(); p.A = vT; p.B = kT; p.Cf = P; p.K = CHK;
    p.lda = ROWS; p.ldb = ROWS; p.aZcol = CHK; p.bZcol = CHK; p.cZrow = E_DIM;
    gemm_mfma<0,0,1,0,0,0,0,0,0,0,0><<<dim3(4,4,B_SZ*NCHK), blk, 0, stream>>>(p);
    ksum_k<<<dim3(B_SZ * NCHK), dim3(512), 0, stream>>>(kT, ks);
    prefix_ks<<<dim3(8), blk, 0, stream>>>(ks);
    prefix_kv<<<dim3(4096), blk, 0, stream>>>(P, PTb);
    // intra-chunk masked scores -> Sc (bf16)
    clr(); p.A = q; p.B = kbuf; p.Cb = Sc; p.K = E_DIM;
    p.ldc = CHK; p.aZrow = CHK; p.bZrow = CHK; p.cZrow = CHK;
    gemm_mfma<0,0,0,1,0,0,0,1,1,0,0><<<dim3(2,2,B_SZ*NCHK), blk, 0, stream>>>(p);
    den_k<<<dim3(ROWS / 4), blk, 0, stream>>>(Sc, q, ks, den);
    // combine: (Sc@vT + q@PTb) / den -> t2b (bf16)
    clr(); p.A = Sc; p.B = vT; p.Cb = t2b; p.den = den;
    p.K = CHK; p.lda = CHK; p.ldb = ROWS; p.aZrow = CHK; p.bZcol = CHK; p.cZrow = CHK;
    p.A2 = q; p.B2 = PTb; p.K2 = E_DIM; p.lda2 = E_DIM; p.ldb2 = E_DIM;
    p.a2Zrow = CHK; p.b2Zrow = E_DIM;
    gemm_mfma<0,0,0,1,0,0,0,0,0,1,1><<<dim3(2,4,B_SZ*NCHK), blk, 0, stream>>>(p);
    // lat += t2b @ Wo^T
    clr(); p.A = t2b; p.B = wob + wOff; p.bias = bo + bOff; p.Cf = lat; p.K = E_DIM;
    gemm_mfma<0,1,1,0,0,0,0,0,0,0,0><<<dim3(64,4), blk, 0, stream>>>(p);
    layernorm_k<<<dim3(ROWS), blk, 0, stream>>>(lat, ln2g + bOff, ln2b + bOff, h);
    // c1 (gelu) -> t2b ; lat += t2b @ c2^T
    clr(); p.A = h; p.B = wc1 + wOff; p.bias = c1b + bOff; p.Cb = t2b; p.K = E_DIM;
    gemm_mfma<2,0,0,1,0,0,0,0,0,0,0><<<dim3(64,4), blk, 0, stream>>>(p);
    clr(); p.A = t2b; p.B = wc2 + wOff; p.bias = c2b + bOff; p.Cf = lat; p.K = E_DIM;
    gemm_mfma<0,1,1,0,0,0,0,0,0,0,0><<<dim3(64,4), blk, 0, stream>>>(p);
  }
  out_proj<<<dim3(S_LEN / 64, 1, B_SZ), blk, 0, stream>>>(lat, oW, ob, out);
}

// Round 3
// 768.203 us; speedup vs baseline: 3.8995x; 1.3376x over previous
//
#include <hip/hip_runtime.h>
#include <hip/hip_bf16.h>
#include <cmath>

#define S_LEN 2048
#define E_DIM 512
#define B_SZ 4
#define CIN_D 64
#define COUT_D 64
#define L_NUM 4
#define CHK 256
#define NCHK 8
#define ROWS (B_SZ * S_LEN)  // 8192
#define PADR 2050            // padded rows per batch for causal conv
#define QLD 1024             // leading dim of fused qk buffer

typedef __attribute__((ext_vector_type(8))) short short8;
typedef __attribute__((ext_vector_type(4))) float f32x4;
typedef unsigned short ushort_t;

__device__ __forceinline__ ushort_t f2b(float v) {
  __hip_bfloat16 t = __float2bfloat16(v);
  return __builtin_bit_cast(ushort_t, t);
}
__device__ __forceinline__ float b2f(ushort_t u) {
  return __builtin_bit_cast(float, ((unsigned)u) << 16);
}

__device__ __forceinline__ void gload16(const void* g, void* l) {
  __builtin_amdgcn_global_load_lds((const __attribute__((address_space(1))) void*)g,
                                   (__attribute__((address_space(3))) void*)l, 16, 0, 0);
}

#define WAIT_BARRIER() asm volatile("s_waitcnt vmcnt(0)\ns_barrier" ::: "memory")

// ======================= universal bf16 MFMA GEMM =======================
// Tile TM x TN, BK=64, 4 waves (2x2), double-buffered LDS, 2-phase prefetch.
struct GemmP {
  const ushort_t* A; const ushort_t* B; const float* bias;
  float* Cf; ushort_t* Cb; const float* den;
  int nkt, lda, ldb, ldc;
  int aZrow, aZcol, bZrow, bZcol, cZrow;
  const ushort_t* A2; const ushort_t* B2;
  int nkt2, lda2, ldb2, a2Zrow, b2Zrow;
};

template <int TM, int TN, bool CONV>
__device__ __forceinline__ void mma_phase(const ushort_t* A, const ushort_t* B,
                                          int nkt, int lda, int ldb, int arow0,
                                          int acol0, int brow0, int bcol0,
                                          char* sm, int tid,
                                          f32x4 (&acc)[TM / 32][TN / 32]) {
  constexpr int MF = TM / 32, NF = TN / 32;
  constexpr int ABY = TM * 128, BBY = TN * 128, BUF = ABY + BBY;
  constexpr int RA = ABY / 4096, RB = BBY / 4096;
  const int lane = tid & 63, w = tid >> 6;
  const int wr = (w >> 1) * (TM / 2), wc = (w & 1) * (TN / 2);
  const int l15 = lane & 15, l4 = lane >> 4;

  auto stage = [&](int kt, int buf) {
    int ar0 = arow0, ac0 = acol0 + (kt << 6);
    if (CONV) {
      ar0 = arow0 + (kt >> 3);
      ac0 = acol0 + ((kt & 7) << 6);
    }
    char* s = sm + buf * BUF;
#pragma unroll
    for (int r = 0; r < RA; ++r) {
      const int f = (r << 12) + (tid << 4);
      const int row = f >> 7, sw = ((((f >> 4) & 7)) ^ (row & 7)) << 3;
      gload16(A + (size_t)(ar0 + row) * lda + ac0 + sw, s + f);
    }
    const int bc0 = bcol0 + (kt << 6);
#pragma unroll
    for (int r = 0; r < RB; ++r) {
      const int f = (r << 12) + (tid << 4);
      const int row = f >> 7, sw = ((((f >> 4) & 7)) ^ (row & 7)) << 3;
      gload16(B + (size_t)(brow0 + row) * ldb + bc0 + sw, s + ABY + f);
    }
  };

  stage(0, 0);
  WAIT_BARRIER();
  int cur = 0;
  for (int kt = 0; kt < nkt; ++kt) {
    if (kt + 1 < nkt) stage(kt + 1, cur ^ 1);  // prefetch next tile
    char* s = sm + cur * BUF;
#pragma unroll
    for (int kk = 0; kk < 2; ++kk) {
      short8 af[MF], bfv[NF];
#pragma unroll
      for (int m = 0; m < MF; ++m) {
        const int rt = wr + (m << 4) + l15;
        af[m] = *(const short8*)(s + rt * 128 +
                                 (((kk << 6) + (l4 << 4)) ^ ((rt & 7) << 4)));
      }
#pragma unroll
      for (int n = 0; n < NF; ++n) {
        const int rt = wc + (n << 4) + l15;
        bfv[n] = *(const short8*)(s + ABY + rt * 128 +
                                  (((kk << 6) + (l4 << 4)) ^ ((rt & 7) << 4)));
      }
#pragma unroll
      for (int m = 0; m < MF; ++m)
#pragma unroll
        for (int n = 0; n < NF; ++n)
          acc[m][n] = __builtin_amdgcn_mfma_f32_16x16x32_bf16(af[m], bfv[n],
                                                              acc[m][n], 0, 0, 0);
    }
    WAIT_BARRIER();
    cur ^= 1;
  }
}

// ACT: 0 none, 1 phi, 2 gelu, 3 phi-if-row<512 (fused k|v)
template <int TM, int TN, int ACT, bool READC, bool WRITEF, bool WRITEB,
          bool PADA, bool PADC, bool BIASROW, bool TRIMASK, bool SKIPUP,
          bool DIVDEN, bool TWOPH, bool CONV>
__global__ __launch_bounds__(256) void gemm_mfma(GemmP p) {
  constexpr int MF = TM / 32, NF = TN / 32;
  __shared__ __align__(16) char smem[2 * (TM + TN) * 128];
  const int tid = threadIdx.x;
  const int bm = blockIdx.x * TM, bn = blockIdx.y * TN, z = blockIdx.z;
  const int lane = tid & 63, w = tid >> 6;
  const int wr = (w >> 1) * (TM / 2), wc = (w & 1) * (TN / 2);
  const int l15 = lane & 15, l4 = lane >> 4;

  if (SKIPUP && bn >= bm + TM) {  // fully-masked tile: zero-fill Cb
#pragma unroll
    for (int m = 0; m < MF; ++m)
#pragma unroll
      for (int j = 0; j < 4; ++j) {
        const int rloc = bm + wr + (m << 4) + (l4 << 2) + j;
        const size_t crow = (size_t)p.cZrow * z + rloc;
#pragma unroll
        for (int n = 0; n < NF; ++n)
          p.Cb[crow * p.ldc + bn + wc + (n << 4) + l15] = 0;
      }
    return;
  }

  f32x4 acc[MF][NF];
#pragma unroll
  for (int m = 0; m < MF; ++m)
#pragma unroll
    for (int n = 0; n < NF; ++n)
#pragma unroll
      for (int j = 0; j < 4; ++j) acc[m][n][j] = 0.f;

  int arow0 = bm + p.aZrow * z;
  if (PADA) arow0 = bm + ((bm >> 11) << 1);  // padded batch base (tap in-phase)
  mma_phase<TM, TN, CONV>(p.A, p.B, p.nkt, p.lda, p.ldb, arow0, p.aZcol * z,
                          bn + p.bZrow * z, p.bZcol * z, smem, tid, acc);
  if (TWOPH)
    mma_phase<TM, TN, false>(p.A2, p.B2, p.nkt2, p.lda2, p.ldb2,
                             bm + p.a2Zrow * z, 0, bn + p.b2Zrow * z, 0, smem,
                             tid, acc);

  float bcol[NF];
  if (p.bias && !BIASROW) {
#pragma unroll
    for (int n = 0; n < NF; ++n) bcol[n] = p.bias[bn + wc + (n << 4) + l15];
  }
  int crow_base = bm;
  if (PADC) crow_base = bm + ((bm >> 11) << 1) + 2;
#pragma unroll
  for (int m = 0; m < MF; ++m) {
#pragma unroll
    for (int j = 0; j < 4; ++j) {
      const int rloc = wr + (m << 4) + (l4 << 2) + j;
      const size_t crow = (size_t)p.cZrow * z + crow_base + rloc;
      float inv = 1.f;
      if (DIVDEN) inv = 1.f / (p.den[crow] + 1e-6f);
      float brbias = 0.f;
      if (BIASROW && p.bias) brbias = p.bias[bm + rloc];
#pragma unroll
      for (int n = 0; n < NF; ++n) {
        const int col = bn + wc + (n << 4) + l15;
        float v = acc[m][n][j];
        if (p.bias) v += BIASROW ? brbias : bcol[n];
        if (ACT == 1) v = v > 0.f ? v + 1.f : __expf(v);
        if (ACT == 2) v = 0.5f * v * (1.f + erff(v * 0.70710678118654752f));
        if (ACT == 3 && (bm + rloc) < 512) v = v > 0.f ? v + 1.f : __expf(v);
        if (TRIMASK) {
          if (col > bm + rloc) v = 0.f;
        }
        const size_t cidx = crow * p.ldc + col;
        if (READC) v += p.Cf[cidx];
        if (DIVDEN) v *= inv;
        if (WRITEF) p.Cf[cidx] = v;
        if (WRITEB) p.Cb[cidx] = f2b(v);
      }
    }
  }
}

// ======================= prep / small kernels =======================

struct CvtP {
  const float *in_W, *cc_W, *Wq, *Wk, *Wv, *Wo, *c1W, *c2W, *bq, *bk, *bv;
  ushort_t *winb, *wconv, *wqkb, *wkvb, *wob, *wc1, *wc2;
  float *bqk, *bkv;
};
__global__ void cvt_all(CvtP c) {
  const size_t NT = 32768 + 786432 + 2097152 * 2 + 1048576 * 3 + 4096 * 2;
  for (size_t i = (size_t)blockIdx.x * 256 + threadIdx.x; i < NT;
       i += (size_t)gridDim.x * 256) {
    size_t j = i;
    if (j < 32768) { c.winb[j] = f2b(c.in_W[j]); continue; }
    j -= 32768;
    if (j < 786432) {  // wconv[n][tap*512+k] = cc_W[n][k][tap]
      size_t n = j / 1536, r = j % 1536;
      c.wconv[j] = f2b(c.cc_W[n * 1536 + (r & 511) * 3 + (r >> 9)]);
      continue;
    }
    j -= 786432;
    if (j < 2097152) {
      size_t l = j >> 19, r = j & 524287, row = r >> 9, k = r & 511;
      c.wqkb[j] = f2b(row < 512 ? c.Wq[l * 262144 + row * 512 + k]
                                : c.Wk[l * 262144 + (row - 512) * 512 + k]);
      continue;
    }
    j -= 2097152;
    if (j < 2097152) {
      size_t l = j >> 19, r = j & 524287, row = r >> 9, k = r & 511;
      c.wkvb[j] = f2b(row < 512 ? c.Wk[l * 262144 + row * 512 + k]
                                : c.Wv[l * 262144 + (row - 512) * 512 + k]);
      continue;
    }
    j -= 2097152;
    if (j < 1048576) { c.wob[j] = f2b(c.Wo[j]); continue; }
    j -= 1048576;
    if (j < 1048576) { c.wc1[j] = f2b(c.c1W[j]); continue; }
    j -= 1048576;
    if (j < 1048576) { c.wc2[j] = f2b(c.c2W[j]); continue; }
    j -= 1048576;
    if (j < 4096) {
      size_t l = j >> 10, r = j & 1023;
      c.bqk[j] = r < 512 ? c.bq[l * 512 + r] : c.bk[l * 512 + r - 512];
      continue;
    }
    j -= 4096;
    {
      size_t l = j >> 10, r = j & 1023;
      c.bkv[j] = r < 512 ? c.bk[l * 512 + r] : c.bv[l * 512 + r - 512];
    }
  }
}

__global__ __launch_bounds__(256) void transpose_x(const float* __restrict__ x,
                                                   ushort_t* __restrict__ xT) {
  __shared__ float t[64][65];
  const int b = blockIdx.z, s0 = blockIdx.x << 6, tid = threadIdx.x;
#pragma unroll
  for (int i = 0; i < 16; ++i) {
    int idx = tid + (i << 8);
    int c = idx >> 6, s = idx & 63;
    t[c][s] = x[(((size_t)(b * CIN_D + c)) << 11) + s0 + s];
  }
  __syncthreads();
#pragma unroll
  for (int i = 0; i < 16; ++i) {
    int idx = tid + (i << 8);
    int s = idx >> 6, c = idx & 63;
    xT[(((size_t)(b * S_LEN + s0 + s)) << 6) + c] = f2b(t[c][s]);
  }
}

__global__ void zpad(ushort_t* __restrict__ t2pad) {
  int i = blockIdx.x * 256 + threadIdx.x;  // 4096
  int b = i >> 10, r = i & 1023;
  t2pad[(size_t)(b * PADR) * E_DIM + r] = 0;
}

__global__ __launch_bounds__(256) void layernorm_k(const float* __restrict__ x,
                                                   const float* __restrict__ g,
                                                   const float* __restrict__ bb,
                                                   ushort_t* __restrict__ y) {
  const int row = blockIdx.x, tid = threadIdx.x;
  const float2 v = *(const float2*)(x + (((size_t)row) << 9) + (tid << 1));
  float s = v.x + v.y, q = v.x * v.x + v.y * v.y;
#pragma unroll
  for (int off = 32; off; off >>= 1) {
    s += __shfl_down(s, off);
    q += __shfl_down(q, off);
  }
  __shared__ float rs[4], rq[4], mv[2];
  const int wid = tid >> 6, lane = tid & 63;
  if (lane == 0) {
    rs[wid] = s;
    rq[wid] = q;
  }
  __syncthreads();
  if (tid == 0) {
    float S_ = rs[0] + rs[1] + rs[2] + rs[3];
    float Q_ = rq[0] + rq[1] + rq[2] + rq[3];
    float m = S_ * (1.f / 512.f);
    float var = Q_ * (1.f / 512.f) - m * m;
    mv[0] = m;
    mv[1] = rsqrtf(var + 1e-5f);
  }
  __syncthreads();
  const float m = mv[0], r = mv[1];
  const int c = tid << 1;
  float ox = (v.x - m) * r * g[c] + bb[c];
  float oy = (v.y - m) * r * g[c + 1] + bb[c + 1];
  unsigned pk = ((unsigned)f2b(oy) << 16) | f2b(ox);
  *(unsigned*)(y + (((size_t)row) << 9) + c) = pk;
}

// ksum[z][e] = sum_t k[z*256+t][e]  (k = qk columns 512..1023)
__global__ void ksum_k(const ushort_t* __restrict__ qk, float* __restrict__ ks) {
  const int z = blockIdx.x, e = threadIdx.x;  // 512 threads
  float s = 0.f;
  for (int t = 0; t < CHK; ++t)
    s += b2f(qk[(size_t)(z * CHK + t) * QLD + 512 + e]);
  ks[(z << 9) + e] = s;
}

__global__ void prefix_ks(float* __restrict__ ks) {
  const int idx = blockIdx.x * 256 + threadIdx.x;  // < B*E
  const int b = idx >> 9, e = idx & 511;
  float acc = 0.f;
#pragma unroll
  for (int j = 0; j < NCHK; ++j) {
    float* p = ks + ((b * NCHK + j) << 9) + e;
    float t = *p;
    *p = acc;
    acc += t;
  }
}

// exclusive prefix over chunks of P (fp32) -> PTb (bf16)
__global__ void prefix_kv(const float* __restrict__ P, ushort_t* __restrict__ PTb) {
  const size_t idx = (size_t)blockIdx.x * 256 + threadIdx.x;  // < B*E*E
  const int b = (int)(idx >> 18);
  const size_t r = idx & ((1u << 18) - 1);
  float acc = 0.f;
#pragma unroll
  for (int j = 0; j < NCHK; ++j) {
    const size_t o = (((size_t)(b * NCHK + j)) << 18) + r;
    PTb[o] = f2b(acc);
    acc += P[o];
  }
}

// den[row] = rowsum(Sc[row]) + q[row] . ks[chunk]
__global__ __launch_bounds__(256) void den_k(const ushort_t* __restrict__ Sc,
                                             const ushort_t* __restrict__ qk,
                                             const float* __restrict__ ks,
                                             float* __restrict__ den) {
  const int wid = threadIdx.x >> 6, lane = threadIdx.x & 63;
  const int row = blockIdx.x * 4 + wid;  // < 8192
  const int z = row >> 8, sl = row & 255;
  const ushort_t* sr = Sc + (((size_t)z) << 16) + (size_t)sl * CHK;
  float s = 0.f;
  for (int t = lane; t < CHK; t += 64) s += b2f(sr[t]);
  const ushort_t* qr = qk + (size_t)row * QLD;
  const float* kp = ks + (z << 9);
  for (int e = lane; e < E_DIM; e += 64) s += b2f(qr[e]) * kp[e];
#pragma unroll
  for (int off = 32; off; off >>= 1) s += __shfl_down(s, off);
  if (lane == 0) den[row] = s;
}

__global__ __launch_bounds__(256) void out_proj(const float* __restrict__ lat,
                                                const float* __restrict__ W,
                                                const float* __restrict__ bias,
                                                float* __restrict__ out) {
  const int b = blockIdx.z, bs = blockIdx.x << 6;
  const int tid = threadIdx.x, tm = tid >> 4, tn = tid & 15;
  const int lr = tid >> 2, lc = (tid & 3) << 2;
  __shared__ float As[16][64], Ws[16][64];
  float acc[4][4] = {{0.f}};
  for (int k0 = 0; k0 < E_DIM; k0 += 16) {
    float4 av =
        *(const float4*)(lat + (((size_t)(b * S_LEN + bs + lr)) << 9) + k0 + lc);
    As[lc + 0][lr] = av.x; As[lc + 1][lr] = av.y;
    As[lc + 2][lr] = av.z; As[lc + 3][lr] = av.w;
    float4 wv = *(const float4*)(W + (((size_t)lr) << 9) + k0 + lc);
    Ws[lc + 0][lr] = wv.x; Ws[lc + 1][lr] = wv.y;
    Ws[lc + 2][lr] = wv.z; Ws[lc + 3][lr] = wv.w;
    __syncthreads();
#pragma unroll
    for (int kk = 0; kk < 16; ++kk) {
      const float4 a4 = *(const float4*)&As[kk][tm << 2];
      const float4 b4 = *(const float4*)&Ws[kk][tn << 2];
      const float aa[4] = {a4.x, a4.y, a4.z, a4.w};
      const float bb[4] = {b4.x, b4.y, b4.z, b4.w};
#pragma unroll
      for (int i = 0; i < 4; ++i)
#pragma unroll
        for (int j2 = 0; j2 < 4; ++j2) acc[i][j2] += aa[i] * bb[j2];
    }
    __syncthreads();
  }
#pragma unroll
  for (int i = 0; i < 4; ++i)
#pragma unroll
    for (int j2 = 0; j2 < 4; ++j2) {
      const int o = (tn << 2) + j2, sl = bs + (tm << 2) + i;
      out[(((size_t)(b * COUT_D + o)) << 11) + sl] = acc[i][j2] + bias[o];
    }
}

// ======================= host launcher =======================
extern "C" void kernel_launch(void* const* d_in, const int* in_sizes, int n_in,
                              void* d_out, int out_size, void* d_ws,
                              size_t ws_size, hipStream_t stream) {
  const float* x = (const float*)d_in[0];
  const float* in_W = (const float*)d_in[1];
  const float* in_b = (const float*)d_in[2];
  const float* cc_W = (const float*)d_in[3];
  const float* cc_b = (const float*)d_in[4];
  const float* ln1g = (const float*)d_in[5];
  const float* ln1b = (const float*)d_in[6];
  const float* ln2g = (const float*)d_in[7];
  const float* ln2b = (const float*)d_in[8];
  const float* Wq = (const float*)d_in[9];
  const float* bq = (const float*)d_in[10];
  const float* Wk = (const float*)d_in[11];
  const float* bk = (const float*)d_in[12];
  const float* Wv = (const float*)d_in[13];
  const float* bv = (const float*)d_in[14];
  const float* Wo = (const float*)d_in[15];
  const float* bo = (const float*)d_in[16];
  const float* c1W = (const float*)d_in[17];
  const float* c1b = (const float*)d_in[18];
  const float* c2W = (const float*)d_in[19];
  const float* c2b = (const float*)d_in[20];
  const float* oW = (const float*)d_in[21];
  const float* ob = (const float*)d_in[22];
  float* out = (float*)d_out;

  const size_t NE = (size_t)ROWS * E_DIM;  // 4194304
  float* lat = (float*)d_ws;
  float* P = lat + NE;       // 8388608 f32
  float* ks = P + 8388608;   // 16384
  float* den = ks + 16384;   // 8192
  float* bqk = den + 8192;   // 4096
  float* bkv = bqk + 4096;   // 4096
  ushort_t* u = (ushort_t*)(bkv + 4096);
  ushort_t* xT = u;     u += (size_t)ROWS * CIN_D;
  ushort_t* t2pad = u;  u += (size_t)B_SZ * PADR * E_DIM;
  ushort_t* h = u;      u += NE;
  ushort_t* qk = u;     u += (size_t)ROWS * QLD;
  ushort_t* kvT = u;    u += (size_t)1024 * ROWS;
  ushort_t* PTb = u;    u += 8388608;
  ushort_t* t2b = u;    u += NE;
  ushort_t* winb = u;   u += 32768;
  ushort_t* wconv = u;  u += 786432;
  ushort_t* wqkb = u;   u += 2097152;
  ushort_t* wkvb = u;   u += 2097152;
  ushort_t* wob = u;    u += 1048576;
  ushort_t* wc1 = u;    u += 1048576;
  ushort_t* wc2 = u;    u += 1048576;
  ushort_t* Sc = (ushort_t*)P;  // alias: P dead after prefix_kv
  ushort_t* kT = kvT;           // rows 0..511
  ushort_t* vT = kvT + (size_t)512 * ROWS;

  const dim3 blk(256);

  CvtP cp{in_W, cc_W, Wq, Wk, Wv, Wo, c1W, c2W, bq, bk, bv,
          winb, wconv, wqkb, wkvb, wob, wc1, wc2, bqk, bkv};
  cvt_all<<<dim3(4096), blk, 0, stream>>>(cp);
  transpose_x<<<dim3(S_LEN / 64, 1, B_SZ), blk, 0, stream>>>(x, xT);
  zpad<<<dim3(16), blk, 0, stream>>>(t2pad);

  GemmP p;
  auto clr = [&]() {
    p = GemmP{};
    p.lda = E_DIM; p.ldb = E_DIM; p.ldc = E_DIM;
  };

  // input projection -> padded bf16 latent (K=64)
  clr(); p.A = xT; p.B = winb; p.bias = in_b; p.Cb = t2pad;
  p.nkt = 1; p.lda = 64; p.ldb = 64;
  gemm_mfma<128,64,0,0,0,1,0,1,0,0,0,0,0,0><<<dim3(64,8), blk, 0, stream>>>(p);
  // fused causal conv: one GEMM, K=1536 (3 taps x 512)
  clr(); p.A = t2pad; p.B = wconv; p.bias = cc_b; p.Cf = lat;
  p.nkt = 24; p.ldb = 1536;
  gemm_mfma<128,64,0,0,1,0,1,0,0,0,0,0,0,1><<<dim3(64,8), blk, 0, stream>>>(p);

  for (int i = 0; i < L_NUM; ++i) {
    const size_t wOff = (size_t)i * E_DIM * E_DIM;
    const size_t bOff = (size_t)i * E_DIM;
    layernorm_k<<<dim3(ROWS), blk, 0, stream>>>(lat, ln1g + bOff, ln1b + bOff, h);
    // fused q|k (phi on both): [8192 x 1024]
    clr(); p.A = h; p.B = wqkb + (size_t)i * 524288; p.bias = bqk + i * 1024;
    p.Cb = qk; p.nkt = 8; p.ldc = QLD;
    gemm_mfma<128,64,1,0,0,1,0,0,0,0,0,0,0,0><<<dim3(64,16), blk, 0, stream>>>(p);
    // fused kT|vT (phi on k rows only): [1024 x 8192]
    clr(); p.A = wkvb + (size_t)i * 524288; p.B = h; p.bias = bkv + i * 1024;
    p.Cb = kvT; p.nkt = 8; p.ldc = ROWS;
    gemm_mfma<64,128,3,0,0,1,0,0,1,0,0,0,0,0><<<dim3(16,64), blk, 0, stream>>>(p);
    // per-chunk PT[e'][e] = sum_t vT[e',t] kT[e,t]
    clr(); p.A = vT; p.B = kT; p.Cf = P; p.nkt = 4;
    p.lda = ROWS; p.ldb = ROWS; p.aZcol = CHK; p.bZcol = CHK; p.cZrow = E_DIM;
    gemm_mfma<128,64,0,0,1,0,0,0,0,0,0,0,0,0><<<dim3(4,8,B_SZ*NCHK), blk, 0, stream>>>(p);
    ksum_k<<<dim3(B_SZ * NCHK), dim3(512), 0, stream>>>(qk, ks);
    prefix_ks<<<dim3(8), blk, 0, stream>>>(ks);
    prefix_kv<<<dim3(4096), blk, 0, stream>>>(P, PTb);
    // intra-chunk masked scores -> Sc (bf16)
    clr(); p.A = qk; p.B = qk + 512; p.Cb = Sc; p.nkt = 8;
    p.lda = QLD; p.ldb = QLD; p.ldc = CHK;
    p.aZrow = CHK; p.bZrow = CHK; p.cZrow = CHK;
    gemm_mfma<128,64,0,0,0,1,0,0,0,1,1,0,0,0><<<dim3(2,4,B_SZ*NCHK), blk, 0, stream>>>(p);
    den_k<<<dim3(ROWS / 4), blk, 0, stream>>>(Sc, qk, ks, den);
    // combine: (Sc@vT + q@PTb) / den -> t2b (bf16)
    clr(); p.A = Sc; p.B = vT; p.Cb = t2b; p.den = den;
    p.nkt = 4; p.lda = CHK; p.ldb = ROWS; p.aZrow = CHK; p.bZcol = CHK; p.cZrow = CHK;
    p.A2 = qk; p.B2 = PTb; p.nkt2 = 8; p.lda2 = QLD; p.ldb2 = E_DIM;
    p.a2Zrow = CHK; p.b2Zrow = E_DIM;
    gemm_mfma<128,64,0,0,0,1,0,0,0,0,0,1,1,0><<<dim3(2,8,B_SZ*NCHK), blk, 0, stream>>>(p);
    // lat += t2b @ Wo^T
    clr(); p.A = t2b; p.B = wob + wOff; p.bias = bo + bOff; p.Cf = lat; p.nkt = 8;
    gemm_mfma<128,64,0,1,1,0,0,0,0,0,0,0,0,0><<<dim3(64,8), blk, 0, stream>>>(p);
    layernorm_k<<<dim3(ROWS), blk, 0, stream>>>(lat, ln2g + bOff, ln2b + bOff, h);
    // c1 (gelu) -> t2b ; lat += t2b @ c2^T
    clr(); p.A = h; p.B = wc1 + wOff; p.bias = c1b + bOff; p.Cb = t2b; p.nkt = 8;
    gemm_mfma<128,64,2,0,0,1,0,0,0,0,0,0,0,0><<<dim3(64,8), blk, 0, stream>>>(p);
    clr(); p.A = t2b; p.B = wc2 + wOff; p.bias = c2b + bOff; p.Cf = lat; p.nkt = 8;
    gemm_mfma<128,64,0,1,1,0,0,0,0,0,0,0,0,0><<<dim3(64,8), blk, 0, stream>>>(p);
  }
  out_proj<<<dim3(S_LEN / 64, 1, B_SZ), blk, 0, stream>>>(lat, oW, ob, out);
}